// Round 11
// baseline (242.686 us; speedup 1.0000x reference)
//
#include <hip/hip_runtime.h>

#define T_DIM 4096
#define J_DIM 24
#define NCI 16
#define NCO 16
#define G_DIM 75
#define CHUNK_T 1024   // t per chunk (64 lanes x 4 segments x 4 floats)

// Inverse of ALL_IDX: for each original joint j, the output g-positions that
// replicate it (conv kernel height is 1, so gathered rows are pure copies).
__device__ const int d_nrep[J_DIM] = {4,3,3,3,3,3,3,3,3,5,3,3,3,3,3,3,3,3,3,3,3,3,3,3};
__device__ const int d_repl[J_DIM][5] = {
  {0, 9, 12, 15, -1},
  {1, 10, 18, -1, -1},
  {2, 13, 21, -1, -1},
  {3, 16, 24, -1, -1},
  {11, 19, 27, -1, -1},
  {14, 22, 30, -1, -1},
  {17, 25, 33, -1, -1},
  {20, 28, 38, -1, -1},
  {23, 31, 40, -1, -1},
  {26, 34, 42, 45, 48},
  {4, 29, 39, -1, -1},
  {5, 32, 41, -1, -1},
  {35, 43, 51, -1, -1},
  {36, 46, 53, -1, -1},
  {37, 49, 56, -1, -1},
  {6, 44, 52, -1, -1},
  {47, 54, 59, -1, -1},
  {50, 57, 62, -1, -1},
  {55, 60, 65, -1, -1},
  {58, 63, 68, -1, -1},
  {61, 66, 71, -1, -1},
  {64, 69, 73, -1, -1},
  {7, 67, 72, -1, -1},
  {8, 70, 74, -1, -1},
};

__device__ __forceinline__ void conv4(float4& a, const float4 v,
                                      const float xm, const float xn,
                                      const float w0, const float w1,
                                      const float w2) {
  a.x = fmaf(xm,  w0, fmaf(v.x, w1, fmaf(v.y, w2, a.x)));
  a.y = fmaf(v.x, w0, fmaf(v.y, w1, fmaf(v.z, w2, a.y)));
  a.z = fmaf(v.y, w0, fmaf(v.z, w1, fmaf(v.w, w2, a.z)));
  a.w = fmaf(v.z, w0, fmaf(v.w, w1, fmaf(xn,  w2, a.w)));
}

__global__ __launch_bounds__(256, 3) void skel_conv(
    const float* __restrict__ x, const float* __restrict__ W,
    const float* __restrict__ bias, float* __restrict__ out) {
  const int jblk = blockIdx.x;   // 0..5
  const int coq  = blockIdx.y;   // 0..3 (co-quad), uniform per block
  const int b    = blockIdx.z;   // batch, uniform per block
  const int tid  = (int)threadIdx.x;
  const int lane = tid & 63;
  // each wave owns one j; j forced to SGPR
  const int j   = __builtin_amdgcn_readfirstlane(jblk * 4 + (tid >> 6));
  const int co0 = coq * 4;

  const int tl = lane * 4;  // lane's float4 offset within a 256-t segment

  const int nrep = d_nrep[j];

  for (int c = 0; c < 4; ++c) {
    const int tc = c * CHUNK_T;

    // acc[cc*4+q]: co = co0+cc, t-segment q (256 t each); init with bias
    float4 acc[16];
#pragma unroll
    for (int cc = 0; cc < 4; ++cc) {
      const float bb = bias[co0 + cc];
#pragma unroll
      for (int q = 0; q < 4; ++q)
        acc[cc * 4 + q] = make_float4(bb, bb, bb, bb);
    }

#pragma unroll 2
    for (int ci = 0; ci < NCI; ++ci) {
      const float* xp = x + (((size_t)b * NCI + ci) * J_DIM + j) * T_DIM;
      // 4 back-to-back 1KB wave loads = 4KB contiguous read burst
      const float4 v0 = *(const float4*)(xp + tc +   0 + tl);
      const float4 v1 = *(const float4*)(xp + tc + 256 + tl);
      const float4 v2 = *(const float4*)(xp + tc + 512 + tl);
      const float4 v3 = *(const float4*)(xp + tc + 768 + tl);

      // left halos (x[t-1]); lane-0 fix from adjacent segment's lane 63
      float m0 = __shfl_up(v0.w, 1);
      float m1 = __shfl_up(v1.w, 1);
      float m2 = __shfl_up(v2.w, 1);
      float m3 = __shfl_up(v3.w, 1);
      const float e1 = __shfl(v0.w, 63);
      const float e2 = __shfl(v1.w, 63);
      const float e3 = __shfl(v2.w, 63);
      if (lane == 0) {
        m0 = (tc > 0) ? xp[tc - 1] : 0.f;
        m1 = e1; m2 = e2; m3 = e3;
      }
      // right halos (x[t+4]); lane-63 fix from adjacent segment's lane 0
      float p0 = __shfl_down(v0.x, 1);
      float p1 = __shfl_down(v1.x, 1);
      float p2 = __shfl_down(v2.x, 1);
      float p3 = __shfl_down(v3.x, 1);
      const float f0 = __shfl(v1.x, 0);
      const float f1 = __shfl(v2.x, 0);
      const float f2 = __shfl(v3.x, 0);
      if (lane == 63) {
        p0 = f0; p1 = f1; p2 = f2;
        p3 = (tc + CHUNK_T < T_DIM) ? xp[tc + CHUNK_T] : 0.f;
      }

#pragma unroll
      for (int cc = 0; cc < 4; ++cc) {
        // uniform indices -> s_load; SGPR operands in the FMAs
        const float w0 = W[((co0 + cc) * NCI + ci) * 3 + 0];
        const float w1 = W[((co0 + cc) * NCI + ci) * 3 + 1];
        const float w2 = W[((co0 + cc) * NCI + ci) * 3 + 2];
        conv4(acc[cc * 4 + 0], v0, m0, p0, w0, w1, w2);
        conv4(acc[cc * 4 + 1], v1, m1, p1, w0, w1, w2);
        conv4(acc[cc * 4 + 2], v2, m2, p2, w0, w1, w2);
        conv4(acc[cc * 4 + 3], v3, m3, p3, w0, w1, w2);
      }
    }

    // store: per (co,g) row, 4 back-to-back 1KB wave stores = 4KB burst
#pragma unroll
    for (int cc = 0; cc < 4; ++cc) {
      for (int r = 0; r < nrep; ++r) {
        const int g = d_repl[j][r];
        float* p = out + (((size_t)b * NCO + co0 + cc) * G_DIM + g) * T_DIM
                       + tc + tl;
        *(float4*)(p +   0) = acc[cc * 4 + 0];
        *(float4*)(p + 256) = acc[cc * 4 + 1];
        *(float4*)(p + 512) = acc[cc * 4 + 2];
        *(float4*)(p + 768) = acc[cc * 4 + 3];
      }
    }
  }
}

extern "C" void kernel_launch(void* const* d_in, const int* in_sizes, int n_in,
                              void* d_out, int out_size, void* d_ws, size_t ws_size,
                              hipStream_t stream) {
  const float* x    = (const float*)d_in[0];
  const float* W    = (const float*)d_in[1];
  const float* bias = (const float*)d_in[2];
  float* out = (float*)d_out;

  dim3 grid(J_DIM / 4, 4, 32);  // 6 x 4 x 32 = 768 blocks, 4 waves each
  dim3 block(256);
  skel_conv<<<grid, block, 0, stream>>>(x, W, bias, out);
}

// Round 13
// 177.267 us; speedup vs baseline: 1.3690x; 1.3690x over previous
//
#include <hip/hip_runtime.h>

#define T_DIM 4096
#define J_DIM 24
#define NCI 16
#define NCO 16
#define G_DIM 75
#define WAVE_T 256            // t-elements per wave (64 lanes x 4)
#define TILE_T (WAVE_T * 4)   // t-elements per block (4 waves)

// Inverse of ALL_IDX: for each original joint j, the output g-positions that
// replicate it (conv kernel height is 1, so gathered rows are pure copies).
__device__ const int d_nrep[J_DIM] = {4,3,3,3,3,3,3,3,3,5,3,3,3,3,3,3,3,3,3,3,3,3,3,3};
__device__ const int d_repl[J_DIM][5] = {
  {0, 9, 12, 15, -1},
  {1, 10, 18, -1, -1},
  {2, 13, 21, -1, -1},
  {3, 16, 24, -1, -1},
  {11, 19, 27, -1, -1},
  {14, 22, 30, -1, -1},
  {17, 25, 33, -1, -1},
  {20, 28, 38, -1, -1},
  {23, 31, 40, -1, -1},
  {26, 34, 42, 45, 48},
  {4, 29, 39, -1, -1},
  {5, 32, 41, -1, -1},
  {35, 43, 51, -1, -1},
  {36, 46, 53, -1, -1},
  {37, 49, 56, -1, -1},
  {6, 44, 52, -1, -1},
  {47, 54, 59, -1, -1},
  {50, 57, 62, -1, -1},
  {55, 60, 65, -1, -1},
  {58, 63, 68, -1, -1},
  {61, 66, 71, -1, -1},
  {64, 69, 73, -1, -1},
  {7, 67, 72, -1, -1},
  {8, 70, 74, -1, -1},
};

__global__ __launch_bounds__(256, 4) void skel_conv(
    const float* __restrict__ x, const float* __restrict__ W,
    const float* __restrict__ bias, float* __restrict__ out) {
  const int tile = blockIdx.x;   // block t-tile (4 tiles of 1024)
  const int j    = blockIdx.y;   // original joint
  const int b    = blockIdx.z;   // batch
  const int tid  = (int)threadIdx.x;
  const int lane = tid & 63;
  // Each WAVE owns a private 256-t slice and computes ALL 16 out-channels
  // -> no two waves anywhere read the same x cache line.
  const int wv = __builtin_amdgcn_readfirstlane(tid >> 6);

  const int t0 = tile * TILE_T + wv * WAVE_T + lane * 4;

  // acc[co], initialized with bias (block-uniform scalar loads)
  float4 acc[NCO];
#pragma unroll
  for (int co = 0; co < NCO; ++co) {
    const float bb = bias[co];
    acc[co] = make_float4(bb, bb, bb, bb);
  }

#pragma unroll 2
  for (int ci = 0; ci < NCI; ++ci) {
    const float* xp = x + (((size_t)b * NCI + ci) * J_DIM + j) * T_DIM;
    const float4 v = *(const float4*)(xp + t0);
    // t-halo via in-wave shuffle; wave-edge lanes patch with a direct load
    float xm1 = __shfl_up(v.w, 1);    // x[t0-1]
    float xp4 = __shfl_down(v.x, 1);  // x[t0+4]
    if (lane == 0)  xm1 = (t0 > 0) ? xp[t0 - 1] : 0.f;
    if (lane == 63) xp4 = (t0 + 4 < T_DIM) ? xp[t0 + 4] : 0.f;

#pragma unroll
    for (int co = 0; co < NCO; ++co) {
      // uniform indices -> s_load; SGPR operands in the FMAs
      const float w0 = W[(co * NCI + ci) * 3 + 0];
      const float w1 = W[(co * NCI + ci) * 3 + 1];
      const float w2 = W[(co * NCI + ci) * 3 + 2];
      acc[co].x = fmaf(xm1, w0, fmaf(v.x, w1, fmaf(v.y, w2, acc[co].x)));
      acc[co].y = fmaf(v.x, w0, fmaf(v.y, w1, fmaf(v.z, w2, acc[co].y)));
      acc[co].z = fmaf(v.y, w0, fmaf(v.z, w1, fmaf(v.w, w2, acc[co].z)));
      acc[co].w = fmaf(v.z, w0, fmaf(v.w, w1, fmaf(xp4, w2, acc[co].w)));
    }
  }

  // Sync the block so all 4 waves enter the store phase in lockstep:
  // the 4 waves' 1KB pieces of each (co,g) row are adjacent t-quarters,
  // so concurrent lockstep stores form 4KB contiguous bursts per row.
  __syncthreads();

  // co-outer / r-inner: consecutive stores are 48-144KB apart (same co
  // region) instead of 1.2MB (co stride) -> tighter DRAM page locality.
  const int nrep = d_nrep[j];
  float* ob = out + (size_t)b * NCO * G_DIM * T_DIM + t0;
#pragma unroll
  for (int co = 0; co < NCO; ++co) {
    float* oc = ob + (size_t)co * (G_DIM * T_DIM);
    for (int r = 0; r < nrep; ++r) {
      const int g = d_repl[j][r];
      *(float4*)(oc + (size_t)g * T_DIM) = acc[co];
    }
  }
}

extern "C" void kernel_launch(void* const* d_in, const int* in_sizes, int n_in,
                              void* d_out, int out_size, void* d_ws, size_t ws_size,
                              hipStream_t stream) {
  const float* x    = (const float*)d_in[0];
  const float* W    = (const float*)d_in[1];
  const float* bias = (const float*)d_in[2];
  float* out = (float*)d_out;

  dim3 grid(T_DIM / TILE_T, J_DIM, 32);  // 4 x 24 x 32 = 3072 blocks
  dim3 block(256);
  skel_conv<<<grid, block, 0, stream>>>(x, W, bias, out);
}